// Round 2
// baseline (127.678 us; speedup 1.0000x reference)
//
#include <hip/hip_runtime.h>
#include <math.h>

#define Bn  16
#define Hn  384
#define Wn  512
#define HWn (Hn * Wn)

typedef float f4 __attribute__((ext_vector_type(4)));

__global__ __launch_bounds__(256) void ProjectionLayer_678604833211_kernel(
    const float* __restrict__ src,    // [B,H,W,3]
    const float* __restrict__ depth,  // [B,H,W]
    const float* __restrict__ pose,   // [B,6]
    const float* __restrict__ intr,   // [3,3]
    float* __restrict__ out)          // [B,H,W,3]
{
    // S[0..11]  = proj rows 0..2 (4 cols each)  (proj = K4 @ T, top 3 rows)
    // S[12..15] = inv_fx, -cx/fx, inv_fy, -cy/fy
    __shared__ float S[16];
    const int b = blockIdx.y;

    if (threadIdx.x == 0) {
        const float fx = intr[0], cx = intr[2], fy = intr[4], cy = intr[5];
        const float tx = pose[b * 6 + 0] * 0.01f;
        const float ty = pose[b * 6 + 1] * 0.01f;
        const float tz = pose[b * 6 + 2] * 0.01f;
        const float rx = pose[b * 6 + 3] * 0.001f;
        const float ry = pose[b * 6 + 4] * 0.001f;
        const float rz = pose[b * 6 + 5] * 0.001f;
        const float cX = cosf(rx), sX = sinf(rx);
        const float cY = cosf(ry), sY = sinf(ry);
        const float cZ = cosf(rz), sZ = sinf(rz);
        // R = (Rz @ Ry) @ Rx   (match reference associativity)
        const float R00 = cZ * cY;
        const float R01 = -sZ * cX + cZ * sY * sX;
        const float R02 =  sZ * sX + cZ * sY * cX;
        const float R10 = sZ * cY;
        const float R11 =  cZ * cX + sZ * sY * sX;
        const float R12 = -cZ * sX + sZ * sY * cX;
        const float R20 = -sY;
        const float R21 = cY * sX;
        const float R22 = cY * cX;
        // proj = K4 @ [R | t]
        S[0]  = fx * R00 + cx * R20;
        S[1]  = fx * R01 + cx * R21;
        S[2]  = fx * R02 + cx * R22;
        S[3]  = fx * tx  + cx * tz;
        S[4]  = fy * R10 + cy * R20;
        S[5]  = fy * R11 + cy * R21;
        S[6]  = fy * R12 + cy * R22;
        S[7]  = fy * ty  + cy * tz;
        S[8]  = R20;
        S[9]  = R21;
        S[10] = R22;
        S[11] = tz;
        S[12] = 1.0f / fx;
        S[13] = -cx / fx;
        S[14] = 1.0f / fy;
        S[15] = -cy / fy;
    }
    __syncthreads();

    // 4 pixels per thread, all in the same image row (512 % 4 == 0).
    const int tid0 = (blockIdx.x * 256 + threadIdx.x) * 4;
    const int u0 = tid0 & (Wn - 1);
    const int v  = tid0 >> 9;  // Wn == 512

    const f4 dvec = __builtin_nontemporal_load(
        (const f4*)(depth + (size_t)b * HWn + tid0));

    const float m0 = S[0],  m1 = S[1],  m2 = S[2],  m3 = S[3];
    const float m4 = S[4],  m5 = S[5],  m6 = S[6],  m7 = S[7];
    const float m8 = S[8],  m9 = S[9],  m10 = S[10], m11 = S[11];
    const float ifx = S[12], nfx = S[13], ify = S[14], nfy = S[15];

    const float camy_unit = fmaf((float)v, ify, nfy);  // camy per unit depth
    const float* base = src + (size_t)b * HWn * 3;

    float o[12];

    #pragma unroll
    for (int j = 0; j < 4; ++j) {
        const float d = dvec[j];
        const float camx = fmaf((float)(u0 + j), ifx, nfx) * d;
        const float camy = camy_unit * d;

        const float p0 = fmaf(m0, camx, fmaf(m1, camy, fmaf(m2,  d, m3)));
        const float p1 = fmaf(m4, camx, fmaf(m5, camy, fmaf(m6,  d, m7)));
        const float p2 = fmaf(m8, camx, fmaf(m9, camy, fmaf(m10, d, m11)));

        const float inv = 1.0f / (p2 + 1e-10f);
        const float x = p0 * inv;
        const float y = p1 * inv;

        const float x0f = floorf(x), y0f = floorf(y);
        const float ax = x - x0f;
        const float ay = y - y0f;
        const float bx = (x0f + 1.0f) - x;   // match reference rounding
        const float by = (y0f + 1.0f) - y;
        const float wa = bx * by;
        const float wb = bx * ay;
        const float wc = ax * by;
        const float wd = ax * ay;

        const int x0 = (int)fminf(fmaxf(x0f,        0.0f), (float)(Wn - 1));
        const int x1 = (int)fminf(fmaxf(x0f + 1.0f, 0.0f), (float)(Wn - 1));
        const int y0 = (int)fminf(fmaxf(y0f,        0.0f), (float)(Hn - 1));
        const int y1 = (int)fminf(fmaxf(y0f + 1.0f, 0.0f), (float)(Hn - 1));

        const float* r0 = base + (size_t)(y0 * Wn + x0) * 3;
        const float* r1 = base + (size_t)(y1 * Wn + x0) * 3;

        float A0, A1, A2, C0, C1, C2, B0, B1, B2, D0, D1, D2;
        if (x1 == x0 + 1) {
            // Interior: left+right taps are 24 contiguous bytes per row.
            float t0[6], t1[6];
            __builtin_memcpy(t0, r0, 24);
            __builtin_memcpy(t1, r1, 24);
            A0 = t0[0]; A1 = t0[1]; A2 = t0[2];
            C0 = t0[3]; C1 = t0[4]; C2 = t0[5];
            B0 = t1[0]; B1 = t1[1]; B2 = t1[2];
            D0 = t1[3]; D1 = t1[4]; D2 = t1[5];
        } else {
            // Clamped: x1 == x0, both taps identical.
            A0 = r0[0]; A1 = r0[1]; A2 = r0[2];
            C0 = A0; C1 = A1; C2 = A2;
            B0 = r1[0]; B1 = r1[1]; B2 = r1[2];
            D0 = B0; D1 = B1; D2 = B2;
        }

        o[j * 3 + 0] = wa * A0 + wb * B0 + wc * C0 + wd * D0;
        o[j * 3 + 1] = wa * A1 + wb * B1 + wc * C1 + wd * D1;
        o[j * 3 + 2] = wa * A2 + wb * B2 + wc * C2 + wd * D2;
    }

    // 48 contiguous bytes, 16B-aligned (tid0 % 4 == 0 -> 12*tid0 % 16 == 0).
    f4* q = (f4*)(out + ((size_t)b * HWn + tid0) * 3);
    f4 s0 = {o[0], o[1], o[2],  o[3]};
    f4 s1 = {o[4], o[5], o[6],  o[7]};
    f4 s2 = {o[8], o[9], o[10], o[11]};
    __builtin_nontemporal_store(s0, q + 0);
    __builtin_nontemporal_store(s1, q + 1);
    __builtin_nontemporal_store(s2, q + 2);
}

extern "C" void kernel_launch(void* const* d_in, const int* in_sizes, int n_in,
                              void* d_out, int out_size, void* d_ws, size_t ws_size,
                              hipStream_t stream) {
    const float* src   = (const float*)d_in[0];  // [16,384,512,3]
    const float* depth = (const float*)d_in[1];  // [16,384,512]
    const float* pose  = (const float*)d_in[2];  // [16,6]
    const float* intr  = (const float*)d_in[3];  // [3,3]
    float* out = (float*)d_out;

    dim3 grid(HWn / (256 * 4), Bn);  // (192, 16)
    dim3 block(256);
    ProjectionLayer_678604833211_kernel<<<grid, block, 0, stream>>>(
        src, depth, pose, intr, out);
}